// Round 4
// baseline (1273.653 us; speedup 1.0000x reference)
//
#include <hip/hip_runtime.h>
#include <hip/hip_bf16.h>
#include <stdint.h>

// ---------------------------------------------------------------------------
// Cosine similarity: C[n][m] = <z_n/||z_n||, cm_m/||cm_m||>
// M=32768 rows z, Ncls=1001 rows cm, K=512, out fp32 [M][Ncls].
// Pass 1 (tiny): normalize cm rows -> bf16 bn [Npad=1024][512] in d_ws.
// Pass 2: ZERO-BARRIER direct-from-global GEMM (R4 rewrite).
//   R0-R3 post-mortem: the LDS staging machine (stage->convert->ds_write->
//   barrier->ds_read, 16 barriers/block) was the bottleneck, not BW or any
//   pipe (all counters <40% while 3 structural variants landed 86-103 us).
//   B (1 MB) and the XCD-shared A panels (256 KB, 8 consecutive siblings)
//   are L2-resident -- staging cache-fit data is pure overhead (guide
//   Common-mistake #7). New structure:
//   - Each wave owns a 64x64 C tile; fragments loaded STRAIGHT from global:
//     A: fp32 32 B/row segments (line-efficient), converted in-register via
//     v_cvt_pk (scalar-cast API), row-ssq accumulated from the fp32 values.
//     B: bn is [n][k] so the MFMA B-operand is a contiguous 16 B load.
//   - K-loop has NO barriers, NO LDS: 16 independent waves/CU hide latency;
//     compiler pipelines with its own counted vmcnt.
//   - One __syncthreads total (row-norm exchange via 512 B LDS).
//   - C stores nontemporal: 131 MB of streaming writes no longer evict the
//     operand working set from the 4 MB per-XCD L2s.
//   - Block 128x128 (4 waves), grid 2048, XCD-chunked swizzle kept.
//   - __launch_bounds__(256,4): <=128 VGPR (acc 64 + frags 32 + staging).
// Workspace need: 1024*512*2 B = 1 MB.
// ---------------------------------------------------------------------------

typedef short short8 __attribute__((ext_vector_type(8)));
typedef float f32x16 __attribute__((ext_vector_type(16)));

#define KDIM 512

__device__ __forceinline__ unsigned short f2bf(float f) {
  uint32_t u = __float_as_uint(f);
  u += 0x7FFFu + ((u >> 16) & 1u);   // round-to-nearest-even
  return (unsigned short)(u >> 16);
}

// One wave per cm row; rows >= Ncls written as zeros (GEMM B-side pad).
__global__ __launch_bounds__(256) void normalize_cm_kernel(
    const float* __restrict__ cm, unsigned short* __restrict__ bn,
    int Ncls, int Npad) {
  int r = blockIdx.x * 4 + (threadIdx.x >> 6);
  int lane = threadIdx.x & 63;
  if (r >= Npad) return;
  unsigned short* dst = bn + (size_t)r * KDIM;
  if (r >= Ncls) {
    uint2 zv = make_uint2(0u, 0u);
    *(uint2*)(dst + lane * 4) = zv;
    *(uint2*)(dst + 256 + lane * 4) = zv;
    return;
  }
  const float4* s4 = (const float4*)(cm + (size_t)r * KDIM);
  float4 x0 = s4[lane];
  float4 x1 = s4[lane + 64];
  float s = x0.x * x0.x + x0.y * x0.y + x0.z * x0.z + x0.w * x0.w +
            x1.x * x1.x + x1.y * x1.y + x1.z * x1.z + x1.w * x1.w;
#pragma unroll
  for (int off = 32; off > 0; off >>= 1) s += __shfl_xor(s, off, 64);
  float scale = 1.0f / fmaxf(sqrtf(s), 1e-8f);

  union { unsigned short u[4]; uint2 v; } p0, p1;
  p0.u[0] = f2bf(x0.x * scale); p0.u[1] = f2bf(x0.y * scale);
  p0.u[2] = f2bf(x0.z * scale); p0.u[3] = f2bf(x0.w * scale);
  p1.u[0] = f2bf(x1.x * scale); p1.u[1] = f2bf(x1.y * scale);
  p1.u[2] = f2bf(x1.z * scale); p1.u[3] = f2bf(x1.w * scale);
  *(uint2*)(dst + lane * 4) = p0.v;
  *(uint2*)(dst + 256 + lane * 4) = p1.v;
}

// Pack 2 fp32 -> 2 bf16 (RNE) in one uint; compiler emits v_cvt_pk_bf16_f32.
__device__ __forceinline__ uint32_t pk2(float a, float b) {
  union { __hip_bfloat162 h; uint32_t u; } c;
  c.h = __float22bfloat162_rn(make_float2(a, b));
  return c.u;
}

// 8 fp32 (2 float4) -> one short8 A-fragment; accumulates ssq into rs.
__device__ __forceinline__ short8 cvt_frag(float4 v0, float4 v1, float& rs) {
  rs += v0.x * v0.x + v0.y * v0.y + v0.z * v0.z + v0.w * v0.w +
        v1.x * v1.x + v1.y * v1.y + v1.z * v1.z + v1.w * v1.w;
  union { uint32_t u[4]; short8 s; } r;
  r.u[0] = pk2(v0.x, v0.y);
  r.u[1] = pk2(v0.z, v0.w);
  r.u[2] = pk2(v1.x, v1.y);
  r.u[3] = pk2(v1.z, v1.w);
  return r.s;
}

#define MFMA(a, b, c) __builtin_amdgcn_mfma_f32_32x32x16_bf16((a), (b), (c), 0, 0, 0)

// C = bf16(Z) * bn^T, rows scaled by 1/max(||Z_row||, 1e-8). No operand LDS.
__global__ __launch_bounds__(256, 4) void gemm_fused_kernel(
    const float* __restrict__ Z,
    const unsigned short* __restrict__ B,
    float* __restrict__ C, int M, int Ncls) {
  __shared__ float ns[128];        // row ||z||^2 exchange (only LDS use)

  const int tid = threadIdx.x;
  const int wave = tid >> 6;       // 0..3
  const int lane = tid & 63;

  // XCD-chunked bijective swizzle (nwg % 8 == 0): XCD k runs a contiguous
  // wg range; the 8 N-siblings of each M-panel are consecutive -> A panel
  // is fetched into that XCD's L2 once and reused 8x.
  const int nwg = gridDim.x;
  const int cpx = nwg >> 3;
  const int bid = blockIdx.x;
  const int wg = (bid & 7) * cpx + (bid >> 3);
  const int m0 = (wg >> 3) * 128;  // 256 M-tiles
  const int n0 = (wg & 7) * 128;   // 8 N-tiles

  const int wm = (wave & 1) * 64;  // wave's M offset within block
  const int wn = (wave >> 1) * 64; // wave's N offset within block

  const int fm = lane & 31;        // fragment row (A: m, B: n)
  const int kh = lane >> 5;        // k-half (8-element sub-slice)

  // Per-lane fragment source pointers (row base + kh*8 folded in).
  const float* Arow0 = Z + (size_t)(m0 + wm + fm) * KDIM + kh * 8;
  const float* Arow1 = Arow0 + (size_t)32 * KDIM;
  const unsigned short* Brow0 = B + (size_t)(n0 + wn + fm) * KDIM + kh * 8;
  const unsigned short* Brow1 = Brow0 + (size_t)32 * KDIM;

  f32x16 acc[2][2] = {};
  float rs0 = 0.0f, rs1 = 0.0f;    // ssq of rows wm+fm / wm+32+fm (kh half)

#pragma unroll
  for (int s = 0; s < KDIM / 32; ++s) {
    const float* a0p = Arow0 + s * 32;
    const float* a1p = Arow1 + s * 32;
    const unsigned short* b0p = Brow0 + s * 32;
    const unsigned short* b1p = Brow1 + s * 32;

    // B fragments: contiguous 16 B/lane (bn is [n][k]), L2-hot (1 MB total).
    short8 b00 = *(const short8*)(b0p);        // ks=0
    short8 b10 = *(const short8*)(b1p);
    short8 b01 = *(const short8*)(b0p + 16);   // ks=1
    short8 b11 = *(const short8*)(b1p + 16);

    // A fragments: fp32 load -> ssq -> cvt_pk bf16, straight to MFMA.
    short8 a00 = cvt_frag(*(const float4*)(a0p),      *(const float4*)(a0p + 4),  rs0);
    short8 a10 = cvt_frag(*(const float4*)(a1p),      *(const float4*)(a1p + 4),  rs1);
    short8 a01 = cvt_frag(*(const float4*)(a0p + 16), *(const float4*)(a0p + 20), rs0);
    short8 a11 = cvt_frag(*(const float4*)(a1p + 16), *(const float4*)(a1p + 20), rs1);

    acc[0][0] = MFMA(a00, b00, acc[0][0]);
    acc[0][1] = MFMA(a00, b10, acc[0][1]);
    acc[1][0] = MFMA(a10, b00, acc[1][0]);
    acc[1][1] = MFMA(a10, b10, acc[1][1]);
    acc[0][0] = MFMA(a01, b01, acc[0][0]);
    acc[0][1] = MFMA(a01, b11, acc[0][1]);
    acc[1][0] = MFMA(a11, b01, acc[1][0]);
    acc[1][1] = MFMA(a11, b11, acc[1][1]);
  }

  // Full row ssq: lane^32 holds the other kh half of the same rows.
  rs0 += __shfl_xor(rs0, 32, 64);
  rs1 += __shfl_xor(rs1, 32, 64);
  // Publish: waves with wn==0 cover all 128 block rows (wm 0/64).
  if ((wave >> 1) == 0 && kh == 0) {
    ns[wm + fm] = rs0;
    ns[wm + 32 + fm] = rs1;
  }
  __syncthreads();

  // Epilogue: C = acc * 1/max(||z_row||, eps), nontemporal stores.
  // C/D layout (32x32): col = lane&31, row = (r&3) + 8*(r>>2) + 4*(lane>>5).
  const int cn = lane & 31;
  const int ch4 = kh * 4;
#pragma unroll
  for (int mi = 0; mi < 2; ++mi) {
    float rn[16];
#pragma unroll
    for (int q = 0; q < 4; ++q) {
      float4 n4 = *(const float4*)&ns[wm + mi * 32 + q * 8 + ch4];
      rn[q * 4 + 0] = 1.0f / fmaxf(sqrtf(n4.x), 1e-8f);
      rn[q * 4 + 1] = 1.0f / fmaxf(sqrtf(n4.y), 1e-8f);
      rn[q * 4 + 2] = 1.0f / fmaxf(sqrtf(n4.z), 1e-8f);
      rn[q * 4 + 3] = 1.0f / fmaxf(sqrtf(n4.w), 1e-8f);
    }
#pragma unroll
    for (int ni = 0; ni < 2; ++ni) {
      int n = n0 + wn + ni * 32 + cn;
      if (n < Ncls) {
        size_t base = (size_t)(m0 + wm + mi * 32 + ch4) * (size_t)Ncls + n;
#pragma unroll
        for (int r = 0; r < 16; ++r) {
          int row = (r & 3) + 8 * (r >> 2);
          __builtin_nontemporal_store(acc[mi][ni][r] * rn[r],
                                      &C[base + (size_t)row * Ncls]);
        }
      }
    }
  }
}

extern "C" void kernel_launch(void* const* d_in, const int* in_sizes, int n_in,
                              void* d_out, int out_size, void* d_ws, size_t ws_size,
                              hipStream_t stream) {
  const float* z  = (const float*)d_in[0];
  const float* cm = (const float*)d_in[1];
  float* out = (float*)d_out;

  const int M    = in_sizes[0] / KDIM;                 // 32768
  const int Ncls = in_sizes[1] / KDIM;                 // 1001
  const int Npad = ((Ncls + 255) / 256) * 256;         // 1024

  unsigned short* bn = (unsigned short*)d_ws;          // 1 MB

  normalize_cm_kernel<<<Npad / 4, 256, 0, stream>>>(cm, bn, Ncls, Npad);

  // 1-D grid, XCD swizzle in-kernel: (M/128) x (Npad/128) = 256 x 8 = 2048.
  const int nwg = (M / 128) * (Npad / 128);            // 2048, % 8 == 0
  gemm_fused_kernel<<<dim3(nwg), 256, 0, stream>>>(z, bn, out, M, Ncls);
}

// Round 5
// 212.422 us; speedup vs baseline: 5.9959x; 5.9959x over previous
//
#include <hip/hip_runtime.h>
#include <hip/hip_bf16.h>
#include <stdint.h>

// ---------------------------------------------------------------------------
// Cosine similarity: C[n][m] = <z_n/||z_n||, cm_m/||cm_m||>
// M=32768 rows z, Ncls=1001 rows cm, K=512, out fp32 [M][Ncls].
// Pass 1 (tiny): normalize cm rows -> bf16 bn [Npad=1024][512] in d_ws.
// Pass 2 (fused): GEMM C = bf16(z) * bn^T scaled by 1/||z_row||.
//
// R5 = R0's kernel (best measured: 86.6 us gemm) byte-identical in the
// K-loop/epilogue, with ONE change: 1-D grid + bijective XCD-chunked
// swizzle so the 4 N-siblings of each M-tile run consecutively on the
// same XCD -> A-panel fetched into that L2 once (R1/R3 proved this cuts
// FETCH 135->41 MB; their independent BK32 restructure caused the dur
// regression and is NOT carried).
// Record: R0 86.6us | R1 103 (swz+BK32) | R3 100 (+fixes) | R4 1150 (no-LDS,
// NT-store write blowup 2.07GB). Lesson: NT scalar stores = 16x write amp;
// plain stores coalesce via L2 write-back.
// Workspace need: 1024*512*2 B = 1 MB.
// ---------------------------------------------------------------------------

typedef short short8 __attribute__((ext_vector_type(8)));
typedef float f32x16 __attribute__((ext_vector_type(16)));

#define KDIM 512
#define BK 64

__device__ __forceinline__ unsigned short f2bf(float f) {
  uint32_t u = __float_as_uint(f);
  u += 0x7FFFu + ((u >> 16) & 1u);   // round-to-nearest-even
  return (unsigned short)(u >> 16);
}

// One wave per cm row; rows >= Ncls written as zeros (GEMM B-side pad).
__global__ __launch_bounds__(256) void normalize_cm_kernel(
    const float* __restrict__ cm, unsigned short* __restrict__ bn,
    int Ncls, int Npad) {
  int r = blockIdx.x * 4 + (threadIdx.x >> 6);
  int lane = threadIdx.x & 63;
  if (r >= Npad) return;
  unsigned short* dst = bn + (size_t)r * KDIM;
  if (r >= Ncls) {
    uint2 zv = make_uint2(0u, 0u);
    *(uint2*)(dst + lane * 4) = zv;
    *(uint2*)(dst + 256 + lane * 4) = zv;
    return;
  }
  const float4* s4 = (const float4*)(cm + (size_t)r * KDIM);
  float4 x0 = s4[lane];
  float4 x1 = s4[lane + 64];
  float s = x0.x * x0.x + x0.y * x0.y + x0.z * x0.z + x0.w * x0.w +
            x1.x * x1.x + x1.y * x1.y + x1.z * x1.z + x1.w * x1.w;
#pragma unroll
  for (int off = 32; off > 0; off >>= 1) s += __shfl_xor(s, off, 64);
  float scale = 1.0f / fmaxf(sqrtf(s), 1e-8f);

  union { unsigned short u[4]; uint2 v; } p0, p1;
  p0.u[0] = f2bf(x0.x * scale); p0.u[1] = f2bf(x0.y * scale);
  p0.u[2] = f2bf(x0.z * scale); p0.u[3] = f2bf(x0.w * scale);
  p1.u[0] = f2bf(x1.x * scale); p1.u[1] = f2bf(x1.y * scale);
  p1.u[2] = f2bf(x1.z * scale); p1.u[3] = f2bf(x1.w * scale);
  *(uint2*)(dst + lane * 4) = p0.v;
  *(uint2*)(dst + 256 + lane * 4) = p1.v;
}

// Fused: C = bf16(Z) * B^T, rows scaled by 1/max(||Z_row||, 1e-8).
// Z: [M][512] fp32, B: [Npad][512] bf16 bits, C: [M][Ncls] f32.
__global__ __launch_bounds__(512, 4) void gemm_fused_kernel(
    const float* __restrict__ Z,
    const unsigned short* __restrict__ B,
    float* __restrict__ C, int M, int Ncls) {
  __shared__ unsigned short As[128 * BK];   // 16 KB (bf16)
  __shared__ unsigned short Bs[256 * BK];   // 32 KB (bf16)
  __shared__ float ns[128];                 // row ||z||^2

  const int tid = threadIdx.x;
  const int wave = tid >> 6;
  const int lane = tid & 63;

  // R5: XCD-chunked bijective swizzle (nwg == 1024, % 8 == 0). XCD k runs
  // a contiguous wg range; within it, the 4 N-siblings of each M-tile are
  // consecutive -> co-resident on one XCD -> A-panel L2-resident.
  const int nwg = gridDim.x;
  const int cpx = nwg >> 3;
  const int bid = blockIdx.x;
  const int wg = (bid & 7) * cpx + (bid >> 3);
  const int m0 = (wg >> 2) * 128;
  const int n0 = (wg & 3) * 256;

  const int wm = (wave & 1) * 64;   // wave's M offset
  const int wn = (wave >> 1) * 64;  // wave's N offset (0..192)

  // Chunk = 8 rows x 64 cols. Lane l: row l>>3, source unit (l&7)^((l>>3)&7)
  // so LDS holds unit' = u ^ (row&7) (conflict-free swizzle, same as R0).
  const int l3 = lane >> 3;
  const int su = (lane & 7) ^ (l3 & 7);

  // A: 2 chunks per wave (16 chunks of the 128-row tile), fp32 source.
  const int chA = wave * 2;
  const float* Ag0 = Z + (size_t)(m0 + chA * 8 + l3) * KDIM + su * 8;
  const float* Ag1 = Z + (size_t)(m0 + (chA + 1) * 8 + l3) * KDIM + su * 8;
  unsigned short* Al0 = &As[chA * 512 + lane * 8];
  unsigned short* Al1 = &As[(chA + 1) * 512 + lane * 8];

  // B: 4 chunks per wave (32 chunks of the 256-row tile), async bf16.
  const unsigned short* Bgp[4];
  unsigned short* Blp[4];
#pragma unroll
  for (int c = 0; c < 4; ++c) {
    int cb = wave * 4 + c;
    Bgp[c] = B + (size_t)(n0 + cb * 8 + l3) * KDIM + su * 8;
    Blp[c] = &Bs[cb * 512 + lane * 8];
  }

  const int fm = lane & 31;        // fragment row (A: m, B: n)
  const int kh = lane >> 5;        // k-half
  const int fx = fm & 7;           // swizzle phase

  f32x16 acc[2][2] = {};
  float rs0 = 0.0f, rs1 = 0.0f;    // per-thread partial row ssq

  // Prologue: prefetch A slice k0=0 into registers.
  float4 p00 = *(const float4*)(Ag0);
  float4 p01 = *(const float4*)(Ag0 + 4);
  float4 p10 = *(const float4*)(Ag1);
  float4 p11 = *(const float4*)(Ag1 + 4);

  for (int k0 = 0; k0 < KDIM; k0 += BK) {
    __syncthreads();  // previous iteration's LDS reads complete
#pragma unroll
    for (int c = 0; c < 4; ++c)
      __builtin_amdgcn_global_load_lds(
          (const __attribute__((address_space(1))) void*)(Bgp[c] + k0),
          (__attribute__((address_space(3))) void*)Blp[c], 16, 0, 0);

    // Convert prefetched A (fp32->bf16), accumulate norms, stage to LDS.
    rs0 += p00.x * p00.x + p00.y * p00.y + p00.z * p00.z + p00.w * p00.w +
           p01.x * p01.x + p01.y * p01.y + p01.z * p01.z + p01.w * p01.w;
    rs1 += p10.x * p10.x + p10.y * p10.y + p10.z * p10.z + p10.w * p10.w +
           p11.x * p11.x + p11.y * p11.y + p11.z * p11.z + p11.w * p11.w;
    union { unsigned short u[8]; uint4 v; } pk;
    pk.u[0] = f2bf(p00.x); pk.u[1] = f2bf(p00.y);
    pk.u[2] = f2bf(p00.z); pk.u[3] = f2bf(p00.w);
    pk.u[4] = f2bf(p01.x); pk.u[5] = f2bf(p01.y);
    pk.u[6] = f2bf(p01.z); pk.u[7] = f2bf(p01.w);
    *(uint4*)Al0 = pk.v;
    pk.u[0] = f2bf(p10.x); pk.u[1] = f2bf(p10.y);
    pk.u[2] = f2bf(p10.z); pk.u[3] = f2bf(p10.w);
    pk.u[4] = f2bf(p11.x); pk.u[5] = f2bf(p11.y);
    pk.u[6] = f2bf(p11.z); pk.u[7] = f2bf(p11.w);
    *(uint4*)Al1 = pk.v;

    __syncthreads();  // staged tiles visible (drains B vmcnt + A lgkm)

    // Prefetch next A slice into registers; latency hides under MFMA.
    int k1 = k0 + BK;
    if (k1 < KDIM) {
      p00 = *(const float4*)(Ag0 + k1);
      p01 = *(const float4*)(Ag0 + k1 + 4);
      p10 = *(const float4*)(Ag1 + k1);
      p11 = *(const float4*)(Ag1 + k1 + 4);
    }

#pragma unroll
    for (int ks = 0; ks < 4; ++ks) {
      int u = ((ks << 1) | kh) ^ fx;
      short8 a0 = *(const short8*)&As[(wm + fm) * BK + u * 8];
      short8 a1 = *(const short8*)&As[(wm + 32 + fm) * BK + u * 8];
      short8 b0 = *(const short8*)&Bs[(wn + fm) * BK + u * 8];
      short8 b1 = *(const short8*)&Bs[(wn + 32 + fm) * BK + u * 8];
      acc[0][0] = __builtin_amdgcn_mfma_f32_32x32x16_bf16(a0, b0, acc[0][0], 0, 0, 0);
      acc[0][1] = __builtin_amdgcn_mfma_f32_32x32x16_bf16(a0, b1, acc[0][1], 0, 0, 0);
      acc[1][0] = __builtin_amdgcn_mfma_f32_32x32x16_bf16(a1, b0, acc[1][0], 0, 0, 0);
      acc[1][1] = __builtin_amdgcn_mfma_f32_32x32x16_bf16(a1, b1, acc[1][1], 0, 0, 0);
    }
  }

  // Finish row norms: reduce across the 8 lanes sharing each row, publish.
#pragma unroll
  for (int off = 1; off < 8; off <<= 1) {
    rs0 += __shfl_xor(rs0, off, 64);
    rs1 += __shfl_xor(rs1, off, 64);
  }
  if ((lane & 7) == 0) {
    ns[chA * 8 + l3] = rs0;       // row of chunk chA
    ns[chA * 8 + 8 + l3] = rs1;   // row of chunk chA+1
  }
  __syncthreads();

  // Epilogue: C = acc * 1/max(||z_row||, eps).
  // C/D layout (32x32): col = lane&31, row = (r&3) + 8*(r>>2) + 4*(lane>>5).
  const int cn = lane & 31;
  const int ch4 = kh * 4;
#pragma unroll
  for (int mi = 0; mi < 2; ++mi) {
    float rn[16];
#pragma unroll
    for (int q = 0; q < 4; ++q) {
      float4 n4 = *(const float4*)&ns[wm + mi * 32 + q * 8 + ch4];
      rn[q * 4 + 0] = 1.0f / fmaxf(sqrtf(n4.x), 1e-8f);
      rn[q * 4 + 1] = 1.0f / fmaxf(sqrtf(n4.y), 1e-8f);
      rn[q * 4 + 2] = 1.0f / fmaxf(sqrtf(n4.z), 1e-8f);
      rn[q * 4 + 3] = 1.0f / fmaxf(sqrtf(n4.w), 1e-8f);
    }
#pragma unroll
    for (int ni = 0; ni < 2; ++ni) {
      int n = n0 + wn + ni * 32 + cn;
      if (n < Ncls) {
        size_t base = (size_t)(m0 + wm + mi * 32 + ch4) * (size_t)Ncls + n;
#pragma unroll
        for (int r = 0; r < 16; ++r) {
          int row = (r & 3) + 8 * (r >> 2);
          C[base + (size_t)row * Ncls] = acc[mi][ni][r] * rn[r];
        }
      }
    }
  }
}

extern "C" void kernel_launch(void* const* d_in, const int* in_sizes, int n_in,
                              void* d_out, int out_size, void* d_ws, size_t ws_size,
                              hipStream_t stream) {
  const float* z  = (const float*)d_in[0];
  const float* cm = (const float*)d_in[1];
  float* out = (float*)d_out;

  const int M    = in_sizes[0] / KDIM;                 // 32768
  const int Ncls = in_sizes[1] / KDIM;                 // 1001
  const int Npad = ((Ncls + 255) / 256) * 256;         // 1024

  unsigned short* bn = (unsigned short*)d_ws;          // 1 MB

  normalize_cm_kernel<<<Npad / 4, 256, 0, stream>>>(cm, bn, Ncls, Npad);

  // 1-D grid, XCD swizzle in-kernel: (M/128) x (Npad/256) = 256 x 4 = 1024.
  const int nwg = (M / 128) * (Npad / 256);            // 1024, % 8 == 0
  gemm_fused_kernel<<<dim3(nwg), 512, 0, stream>>>(z, bn, out, M, Ncls);
}